// Round 9
// baseline (768.281 us; speedup 1.0000x reference)
//
#include <hip/hip_runtime.h>
#include <float.h>

// Problem shape (fixed by setup_inputs): x[32768,512], embed[4096,512]
#define D 512
#define NPTS 32768
#define KCODES 4096
#define EPSV 1e-6f

typedef __attribute__((ext_vector_type(8))) short short8;
typedef __attribute__((ext_vector_type(4))) float f32x4;
typedef unsigned short u16;
typedef __attribute__((ext_vector_type(8))) unsigned short u16x8;

// ---------------------------------------------------------------------------
// async global->LDS, 16B per lane (dest = wave-uniform base + lane*16)
__device__ __forceinline__ void async16(void* lds, const void* gl) {
    __builtin_amdgcn_global_load_lds(
        (const __attribute__((address_space(1))) unsigned int*)gl,
        (__attribute__((address_space(3))) unsigned int*)lds,
        16, 0, 0);
}

// fp32 -> bf16 round-to-nearest-even
__device__ __forceinline__ unsigned short f2bf(float f) {
    unsigned int u = __float_as_uint(f);
    u += 0x7fffu + ((u >> 16) & 1u);
    return (unsigned short)(u >> 16);
}

__global__ void cvt_bf16_kernel(const float* __restrict__ in, u16* __restrict__ out) {
    size_t i = (size_t)(blockIdx.x * 256 + threadIdx.x) * 8;
    float4 a = *(const float4*)(in + i);
    float4 b = *(const float4*)(in + i + 4);
    u16x8 r = { f2bf(a.x), f2bf(a.y), f2bf(a.z), f2bf(a.w),
                f2bf(b.x), f2bf(b.y), f2bf(b.z), f2bf(b.w) };
    *(u16x8*)(out + i) = r;
}

// ---------------------------------------------------------------------------
// Bit-exact emulation of numpy fp32 pairwise sum of squares over a 512-row.
// (verified passing - do not change)
__device__ __forceinline__ float np_sumsq_512(const float* __restrict__ row, int l) {
    int b = l >> 3, j = l & 7;
    int base = b * 128 + j;
    float a = row[base];
    float r = __fmul_rn(a, a);
#pragma unroll
    for (int t = 1; t < 16; ++t) {
        float v = row[base + 8 * t];
        r = __fadd_rn(r, __fmul_rn(v, v));
    }
#pragma unroll
    for (int off = 1; off <= 16; off <<= 1)
        r = __fadd_rn(r, __shfl_xor(r, off));
    return r;
}

__global__ void xx_np_kernel(const float* __restrict__ x, float* __restrict__ xx_np) {
    int w = threadIdx.x >> 6, lane = threadIdx.x & 63;
    int hf = lane >> 5, l = lane & 31;
    int p = blockIdx.x * 8 + w * 2 + hf;
    float r = np_sumsq_512(x + (size_t)p * D, l);
    if (l == 0) xx_np[p] = r;
}

__global__ void ee_np_kernel(const float* __restrict__ emb, float* __restrict__ ee_np) {
    int w = threadIdx.x >> 6, lane = threadIdx.x & 63;
    int hf = lane >> 5, l = lane & 31;
    int k = blockIdx.x * 8 + w * 2 + hf;
    float r = np_sumsq_512(emb + (size_t)k * D, l);
    if (l == 0) ee_np[k] = r;
}

// ---------------------------------------------------------------------------
// fused EMA inits (one launch): nea = ea*decay over K*D; ncs = cs*decay over K
__global__ void init_kernel(const float* __restrict__ cs, const float* __restrict__ ea,
                            const float* __restrict__ decay_p,
                            float* __restrict__ ncs, float* __restrict__ nea) {
    int i = blockIdx.x * 256 + threadIdx.x;
    float dv = decay_p[0];
    nea[i] = ea[i] * dv;
    if (i < KCODES) ncs[i] = cs[i] * dv;
}

// ---------------------------------------------------------------------------
// bf16 MFMA screen: scores s[n][k] = ee[k] - 2*dot(x_n, e_k).
// Grid (NPTS/128, 8): block = 128 pts x 512 codes (one code-eighth), 4
// chunks of 128 codes (64 K-steps); emits approx-top-4 (exact top-2) per
// (point, eighth) into 32-slot scrO/idxO.
// Finer jobs (2048) balance the 3-blocks/CU schedule: phases 768@3 / 768@3 /
// 512@2 instead of a 256-block tail at 1-resident.
// K-loop: TRIPLE-buffered LDS, 2-steps-ahead staging, counted s_waitcnt
// vmcnt(4) per step. ee[] staged to an LDS table (off the vmcnt FIFO).
// LDS chunk-XOR-swizzle p = kc ^ ((row>>2)&3) keeps frag ds_read_b128
// 2-way-per-bank (free, m136). ds_read per-lane offsets hoisted.
// __launch_bounds__(256, 3): round-7 counters showed 2 blocks/CU (Occ 21%,
// MfmaUtil 20% = exactly the 2-resident MFMA floor) with only ~164/512 regs
// used; 3 waves/EU caps unified regs at 170 -> 3 blocks/CU (m97's operating
// point, MfmaUtil 37%). Round-3 lesson: (256,4)=128 regs spilled; 170 fits.
#define INS4(s_, c_)  do {                                                  \
    bool l0 = (s_) < m0, l1 = (s_) < m1, l2 = (s_) < m2, l3 = (s_) < m3;    \
    m3 = l2 ? m2 : (l3 ? (s_) : m3);  q3 = l2 ? q2 : (l3 ? (c_) : q3);      \
    m2 = l1 ? m1 : (l2 ? (s_) : m2);  q2 = l1 ? q1 : (l2 ? (c_) : q2);      \
    m1 = l0 ? m0 : (l1 ? (s_) : m1);  q1 = l0 ? q0 : (l1 ? (c_) : q1);      \
    m0 = l0 ? (s_) : m0;              q0 = l0 ? (c_) : q0;                  \
} while (0)

__global__ __launch_bounds__(256, 3)
void screen_kernel(const u16* __restrict__ xb, const u16* __restrict__ eb,
                   const float* __restrict__ ee,
                   float* __restrict__ scrO, int* __restrict__ idxO) {
    // [buf 0..2][A/B][128 rows * 32 k] bf16 = 48 KiB; reduction arrays alias
    // buffer 0 after the K loop (dead by then). eeS: 2 KiB ee table.
    __shared__ __align__(16) u16 S[3][2][128 * 32];
    __shared__ float eeS[512];

    const int tid = threadIdx.x;
    const int w = tid >> 6, lane = tid & 63;
    const int wy = w >> 1, wx = w & 1;
    const int tx = lane & 15, g = lane >> 4;
    const int n0 = blockIdx.x * 128;
    const int hf = blockIdx.y;                 // code eighth 0..7
    const int hbase = hf * 512;

    // per-lane running top-2 per row-slot (fi*4+r)
    float v1[16], v2[16];
    int   i1[16], i2[16];
#pragma unroll
    for (int s = 0; s < 16; ++s) { v1[s] = FLT_MAX; v2[s] = FLT_MAX; i1[s] = 0; i2[s] = 0; }

    // hoisted per-lane ds_read element offsets (within one buffer's A/B region)
    int aoff[4], boff[4];
#pragma unroll
    for (int fi = 0; fi < 4; ++fi) {
        int row = wy * 64 + 16 * fi + tx;
        int ph = g ^ ((row >> 2) & 3);
        aoff[fi] = row * 32 + ph * 8;
    }
#pragma unroll
    for (int fj = 0; fj < 4; ++fj) {
        int row = wx * 64 + 16 * fj + tx;
        int ph = g ^ ((row >> 2) & 3);
        boff[fj] = 4096 + row * 32 + ph * 8;   // B region is +4096 elems
    }
    const int eoff = wx * 64 + tx;             // per-lane ee table offset

    // staging lane constants: instr t covers rows [16t,16t+16); lane l ->
    // row 16t+(l>>2), physical 16B-chunk l&3 holds logical chunk (l&3)^(l>>4)
    const int kc = (lane & 3) ^ (lane >> 4);
    const int srow = lane >> 2;
    const int ta = 2 * w, tb = 2 * w + 1;
    const size_t aoa = (size_t)(n0 + 16 * ta + srow) * D + kc * 8;
    const size_t aob = (size_t)(n0 + 16 * tb + srow) * D + kc * 8;
    const size_t boa = (size_t)(hbase + 16 * ta + srow) * D + kc * 8;
    const size_t bob = (size_t)(hbase + 16 * tb + srow) * D + kc * 8;

    auto stage = [&](int s, int p) {
        const int ch = s >> 4;
        const size_t ko = (size_t)((s & 15) * 32);
        const size_t co = (size_t)ch * (128 * D);
        async16(&S[p][0][ta * 512], xb + aoa + ko);
        async16(&S[p][0][tb * 512], xb + aob + ko);
        async16(&S[p][1][ta * 512], eb + boa + co + ko);
        async16(&S[p][1][tb * 512], eb + bob + co + ko);
    };

    // ee -> LDS table (512 entries for this eighth); compiler drains these
    // global loads before the ds_writes, so they stay off the staging FIFO.
#pragma unroll
    for (int q = 0; q < 2; ++q) eeS[tid + 256 * q] = ee[hbase + tid + 256 * q];

    // prologue: fill buffers 0 and 1; drain buffer 0 only (counted wait).
    stage(0, 0);
    stage(1, 1);
    asm volatile("s_waitcnt vmcnt(4)" ::: "memory");
    __builtin_amdgcn_s_barrier();

    const u16* Sbase = &S[0][0][0];

    for (int c = 0; c < 4; ++c) {
        f32x4 acc[4][4];
#pragma unroll
        for (int fi = 0; fi < 4; ++fi)
#pragma unroll
            for (int fj = 0; fj < 4; ++fj) acc[fi][fj] = (f32x4){0.f, 0.f, 0.f, 0.f};

        for (int kk = 0; kk < 16; ++kk) {
            const int s = c * 16 + kk;
            const u16* bp = Sbase + (s % 3) * 8192;   // uniform base, SALU

            // ds_read current buffer (stage(s) drained at end of step s-1)
            short8 af[4], bf[4];
#pragma unroll
            for (int fi = 0; fi < 4; ++fi) af[fi] = *(const short8*)(bp + aoff[fi]);
#pragma unroll
            for (int fj = 0; fj < 4; ++fj) bf[fj] = *(const short8*)(bp + boff[fj]);

            // issue stage(s+2): stays in flight across ~2 full steps
            if (s < 62) stage(s + 2, (s + 2) % 3);

#pragma unroll
            for (int fi = 0; fi < 4; ++fi)
#pragma unroll
                for (int fj = 0; fj < 4; ++fj)
                    acc[fi][fj] = __builtin_amdgcn_mfma_f32_16x16x32_bf16(
                        af[fi], bf[fj], acc[fi][fj], 0, 0, 0);

            if (kk == 15) {
                // chunk epilogue: fold scores into per-lane top-2; ee via LDS
#pragma unroll
                for (int fj = 0; fj < 4; ++fj) {
                    int col = hbase + c * 128 + wx * 64 + 16 * fj + tx;
                    float ev = eeS[c * 128 + eoff + 16 * fj];
#pragma unroll
                    for (int fi = 0; fi < 4; ++fi)
#pragma unroll
                        for (int r = 0; r < 4; ++r) {
                            float sc = fmaf(-2.0f, acc[fi][fj][r], ev);
                            const int slot = fi * 4 + r;
                            bool b1 = sc < v1[slot];
                            bool b2 = sc < v2[slot];
                            float ov = v1[slot]; int oi = i1[slot];
                            v1[slot] = b1 ? sc : ov;
                            i1[slot] = b1 ? col : oi;
                            v2[slot] = b1 ? ov : (b2 ? sc : v2[slot]);
                            i2[slot] = b1 ? oi : (b2 ? col : i2[slot]);
                        }
                }
            }

            // counted wait: drain stage(s+1) only, keep stage(s+2) in flight.
            // Tail (s>=62): no deeper stages outstanding -> full drain.
            if (s < 62) { asm volatile("s_waitcnt vmcnt(4)" ::: "memory"); }
            else        { asm volatile("s_waitcnt vmcnt(0)" ::: "memory"); }
            __builtin_amdgcn_s_barrier();
        }
    }

    // cross-lane: per row, approx-top-4 (exact top-2) over the wave's 64 cols.
    // Reduction arrays alias dead tile LDS (within buffer 0's regions).
    float (*s_scr)[2][4] = reinterpret_cast<float (*)[2][4]>(&S[0][0][0]);
    int   (*s_idx)[2][4] = reinterpret_cast<int (*)[2][4]>(&S[0][1][0]);

#pragma unroll
    for (int fi = 0; fi < 4; ++fi) {
#pragma unroll
        for (int r = 0; r < 4; ++r) {
            const int slot = fi * 4 + r;
            float m0 = v1[slot], m1 = v2[slot], m2 = FLT_MAX, m3 = FLT_MAX;
            int   q0 = i1[slot], q1 = i2[slot], q2 = 0, q3 = 0;
#pragma unroll
            for (int off = 1; off <= 8; off <<= 1) {
                float o0 = __shfl_xor(m0, off), o1 = __shfl_xor(m1, off);
                float o2 = __shfl_xor(m2, off), o3 = __shfl_xor(m3, off);
                int   p0 = __shfl_xor(q0, off), p1 = __shfl_xor(q1, off);
                int   p2 = __shfl_xor(q2, off), p3 = __shfl_xor(q3, off);
                INS4(o0, p0); INS4(o1, p1); INS4(o2, p2); INS4(o3, p3);
            }
            if (tx == 0) {
                int row = wy * 64 + 16 * fi + 4 * g + r;
                s_scr[row][wx][0] = m0; s_scr[row][wx][1] = m1;
                s_scr[row][wx][2] = m2; s_scr[row][wx][3] = m3;
                s_idx[row][wx][0] = q0; s_idx[row][wx][1] = q1;
                s_idx[row][wx][2] = q2; s_idx[row][wx][3] = q3;
            }
        }
    }
    __syncthreads();
    if (tid < 128) {
        float m0 = s_scr[tid][0][0], m1 = s_scr[tid][0][1],
              m2 = s_scr[tid][0][2], m3 = s_scr[tid][0][3];
        int   q0 = s_idx[tid][0][0], q1 = s_idx[tid][0][1],
              q2 = s_idx[tid][0][2], q3 = s_idx[tid][0][3];
#pragma unroll
        for (int q = 0; q < 4; ++q) INS4(s_scr[tid][1][q], s_idx[tid][1][q]);
        int pt = n0 + tid;
        scrO[(hf * 4 + 0) * NPTS + pt] = m0; idxO[(hf * 4 + 0) * NPTS + pt] = q0;
        scrO[(hf * 4 + 1) * NPTS + pt] = m1; idxO[(hf * 4 + 1) * NPTS + pt] = q1;
        scrO[(hf * 4 + 2) * NPTS + pt] = m2; idxO[(hf * 4 + 2) * NPTS + pt] = q2;
        scrO[(hf * 4 + 3) * NPTS + pt] = m3; idxO[(hf * 4 + 3) * NPTS + pt] = q3;
    }
}

// ---------------------------------------------------------------------------
// merge the eight eighths' top-4 into global screen top-4 per point
__global__ void merge32_kernel(const float* __restrict__ scrO, const int* __restrict__ idxO,
                               int* __restrict__ cand) {
    int n = blockIdx.x * 256 + threadIdx.x;
    float m0 = FLT_MAX, m1 = FLT_MAX, m2 = FLT_MAX, m3 = FLT_MAX;
    int   q0 = 0, q1 = 0, q2 = 0, q3 = 0;
#pragma unroll
    for (int c = 0; c < 32; ++c) {
        float s = scrO[c * NPTS + n];
        int   i = idxO[c * NPTS + n];
        INS4(s, i);
    }
    cand[0 * NPTS + n] = q0; cand[1 * NPTS + n] = q1;
    cand[2 * NPTS + n] = q2; cand[3 * NPTS + n] = q3;
}

// ---------------------------------------------------------------------------
// Final selection emulating numpy fp32 (verified passing - unchanged)
__global__ void rescore_kernel(const float* __restrict__ x, const float* __restrict__ emb,
                               const int* __restrict__ cand,
                               const float* __restrict__ xx_np,
                               const float* __restrict__ ee_np,
                               float* __restrict__ ind_f,
                               float* __restrict__ ncs, const float* __restrict__ decay_p) {
    int w = threadIdx.x >> 6, lane = threadIdx.x & 63;
    int n = blockIdx.x * 4 + w;
    float xxv = xx_np[n];
    float bestd = FLT_MAX; int bidx = 0x7fffffff;
#pragma unroll
    for (int c = 0; c < 4; ++c) {
        int k = cand[c * NPTS + n];
        double acc = 0.0;
#pragma unroll
        for (int i = 0; i < 8; ++i) {
            int d = lane + i * 64;
            acc += (double)emb[(size_t)k * D + d] * (double)x[(size_t)n * D + d];
        }
#pragma unroll
        for (int off = 32; off >= 1; off >>= 1) acc += __shfl_xor(acc, off);
        float mf = (float)acc;
        float t  = __fmul_rn(2.0f, mf);
        float u  = __fsub_rn(xxv, t);
        float dd = __fadd_rn(u, ee_np[k]);
        if (dd < bestd || (dd == bestd && k < bidx)) { bestd = dd; bidx = k; }
    }
    if (lane == 0) {
        ind_f[n] = (float)bidx;
        atomicAdd(&ncs[bidx], 1.0f - decay_p[0]);
    }
}

// ---------------------------------------------------------------------------
__global__ void gather_scatter_kernel(const float* __restrict__ x,
                                      const float* __restrict__ emb,
                                      const float* __restrict__ ind_f,
                                      float* __restrict__ quant, float* __restrict__ nea,
                                      const float* __restrict__ decay_p) {
    int gid = blockIdx.x * 256 + threadIdx.x;   // NPTS * (D/4)
    int n = gid >> 7, dq = gid & 127;
    int k = (int)ind_f[n];
    float4 e4 = *(const float4*)(emb + (size_t)k * D + dq * 4);
    *(float4*)(quant + (size_t)n * D + dq * 4) = e4;
    float4 x4 = *(const float4*)(x + (size_t)n * D + dq * 4);
    float wgt = 1.0f - decay_p[0];
    float* base = nea + (size_t)k * D + dq * 4;
    atomicAdd(base + 0, x4.x * wgt);
    atomicAdd(base + 1, x4.y * wgt);
    atomicAdd(base + 2, x4.z * wgt);
    atomicAdd(base + 3, x4.w * wgt);
}

// ---------------------------------------------------------------------------
__global__ void total_kernel(const float* __restrict__ ncs, float* __restrict__ total) {
    __shared__ float sd[1024];
    int t = threadIdx.x;
    sd[t] = ncs[t] + ncs[t + 1024] + ncs[t + 2048] + ncs[t + 3072];
    __syncthreads();
    for (int st = 512; st > 0; st >>= 1) {
        if (t < st) sd[t] += sd[t + st];
        __syncthreads();
    }
    if (t == 0) total[0] = sd[0];
}

__global__ void new_embed_kernel(const float* __restrict__ nea, const float* __restrict__ ncs,
                                 const float* __restrict__ total, float* __restrict__ ne) {
    int i = blockIdx.x * 256 + threadIdx.x;   // K*D
    int k = i >> 9;
    float t = total[0];
    float sm = (ncs[k] + EPSV) / (t + EPSV * (float)KCODES) * t;
    ne[i] = nea[i] / sm;
}

// ---------------------------------------------------------------------------
extern "C" void kernel_launch(void* const* d_in, const int* in_sizes, int n_in,
                              void* d_out, int out_size, void* d_ws, size_t ws_size,
                              hipStream_t stream) {
    const float* x     = (const float*)d_in[0];
    const float* emb   = (const float*)d_in[1];
    const float* cs    = (const float*)d_in[2];
    const float* ea    = (const float*)d_in[3];
    const float* decay = (const float*)d_in[4];

    float* out   = (float*)d_out;
    float* quant = out;                               // NPTS*D
    float* ind_f = out + (size_t)NPTS * D;            // NPTS
    float* ncs   = ind_f + NPTS;                      // KCODES
    float* nea   = ncs + KCODES;                      // KCODES*D
    float* ne    = nea + (size_t)KCODES * D;          // KCODES*D

    float* ws    = (float*)d_ws;
    float* ee_np = ws;                                // KCODES
    float* xx_np = ws + KCODES;                       // NPTS
    float* hold0 = xx_np + NPTS;                      // (layout hold, unused)
    int*   hold1 = (int*)(hold0 + 16 * (size_t)NPTS); // (layout hold, unused)
    int*   cand  = hold1 + 16 * (size_t)NPTS;         // 4*NPTS
    u16*   eb    = (u16*)(cand + 4 * (size_t)NPTS);   // KCODES*D bf16 (16B-aligned)
    float* total = (float*)(eb + (size_t)KCODES * D); // 1

    // bf16 x staged in the LOWER half of the quant output region; scr32/idx32
    // live in the UPPER half (both dead before gather_scatter writes quant).
    u16*   xb    = (u16*)quant;                       // NPTS*D bf16 = 32MB
    float* scr32 = quant + (size_t)NPTS * D / 2;      // 32*NPTS floats
    int*   idx32 = (int*)(scr32 + 32 * (size_t)NPTS); // 32*NPTS ints

    hipLaunchKernelGGL(cvt_bf16_kernel, dim3(NPTS * D / 2048),   dim3(256), 0, stream, x, xb);
    hipLaunchKernelGGL(cvt_bf16_kernel, dim3(KCODES * D / 2048), dim3(256), 0, stream, emb, eb);
    hipLaunchKernelGGL(ee_np_kernel,    dim3(KCODES / 8),        dim3(256), 0, stream, emb, ee_np);
    hipLaunchKernelGGL(xx_np_kernel,    dim3(NPTS / 8),          dim3(256), 0, stream, x, xx_np);
    hipLaunchKernelGGL(init_kernel,     dim3(KCODES * (D / 256)), dim3(256), 0, stream, cs, ea, decay, ncs, nea);
    hipLaunchKernelGGL(screen_kernel,   dim3(NPTS / 128, 8),     dim3(256), 0, stream,
                       xb, eb, ee_np, scr32, idx32);
    hipLaunchKernelGGL(merge32_kernel,  dim3(NPTS / 256),        dim3(256), 0, stream, scr32, idx32, cand);
    hipLaunchKernelGGL(rescore_kernel,  dim3(NPTS / 4),          dim3(256), 0, stream,
                       x, emb, cand, xx_np, ee_np, ind_f, ncs, decay);
    hipLaunchKernelGGL(gather_scatter_kernel, dim3(NPTS * (D / 4) / 256), dim3(256), 0, stream,
                       x, emb, ind_f, quant, nea, decay);
    hipLaunchKernelGGL(total_kernel,    dim3(1),                 dim3(1024), 0, stream, ncs, total);
    hipLaunchKernelGGL(new_embed_kernel, dim3(KCODES * (D / 256)), dim3(256), 0, stream, nea, ncs, total, ne);
}

// Round 10
// 636.964 us; speedup vs baseline: 1.2062x; 1.2062x over previous
//
#include <hip/hip_runtime.h>
#include <float.h>

// Problem shape (fixed by setup_inputs): x[32768,512], embed[4096,512]
#define D 512
#define NPTS 32768
#define KCODES 4096
#define EPSV 1e-6f

typedef __attribute__((ext_vector_type(8))) short short8;
typedef __attribute__((ext_vector_type(4))) float f32x4;
typedef unsigned short u16;
typedef __attribute__((ext_vector_type(8))) unsigned short u16x8;

// ---------------------------------------------------------------------------
// async global->LDS, 16B per lane (dest = wave-uniform base + lane*16)
__device__ __forceinline__ void async16(void* lds, const void* gl) {
    __builtin_amdgcn_global_load_lds(
        (const __attribute__((address_space(1))) unsigned int*)gl,
        (__attribute__((address_space(3))) unsigned int*)lds,
        16, 0, 0);
}

// fp32 -> bf16 round-to-nearest-even
__device__ __forceinline__ unsigned short f2bf(float f) {
    unsigned int u = __float_as_uint(f);
    u += 0x7fffu + ((u >> 16) & 1u);
    return (unsigned short)(u >> 16);
}

__global__ void cvt_bf16_kernel(const float* __restrict__ in, u16* __restrict__ out) {
    size_t i = (size_t)(blockIdx.x * 256 + threadIdx.x) * 8;
    float4 a = *(const float4*)(in + i);
    float4 b = *(const float4*)(in + i + 4);
    u16x8 r = { f2bf(a.x), f2bf(a.y), f2bf(a.z), f2bf(a.w),
                f2bf(b.x), f2bf(b.y), f2bf(b.z), f2bf(b.w) };
    *(u16x8*)(out + i) = r;
}

// ---------------------------------------------------------------------------
// Bit-exact emulation of numpy fp32 pairwise sum of squares over a 512-row.
// (verified passing - do not change)
__device__ __forceinline__ float np_sumsq_512(const float* __restrict__ row, int l) {
    int b = l >> 3, j = l & 7;
    int base = b * 128 + j;
    float a = row[base];
    float r = __fmul_rn(a, a);
#pragma unroll
    for (int t = 1; t < 16; ++t) {
        float v = row[base + 8 * t];
        r = __fadd_rn(r, __fmul_rn(v, v));
    }
#pragma unroll
    for (int off = 1; off <= 16; off <<= 1)
        r = __fadd_rn(r, __shfl_xor(r, off));
    return r;
}

__global__ void xx_np_kernel(const float* __restrict__ x, float* __restrict__ xx_np) {
    int w = threadIdx.x >> 6, lane = threadIdx.x & 63;
    int hf = lane >> 5, l = lane & 31;
    int p = blockIdx.x * 8 + w * 2 + hf;
    float r = np_sumsq_512(x + (size_t)p * D, l);
    if (l == 0) xx_np[p] = r;
}

__global__ void ee_np_kernel(const float* __restrict__ emb, float* __restrict__ ee_np) {
    int w = threadIdx.x >> 6, lane = threadIdx.x & 63;
    int hf = lane >> 5, l = lane & 31;
    int k = blockIdx.x * 8 + w * 2 + hf;
    float r = np_sumsq_512(emb + (size_t)k * D, l);
    if (l == 0) ee_np[k] = r;
}

// ---------------------------------------------------------------------------
// fused EMA inits (one launch): nea = ea*decay over K*D; ncs = cs*decay over K
__global__ void init_kernel(const float* __restrict__ cs, const float* __restrict__ ea,
                            const float* __restrict__ decay_p,
                            float* __restrict__ ncs, float* __restrict__ nea) {
    int i = blockIdx.x * 256 + threadIdx.x;
    float dv = decay_p[0];
    nea[i] = ea[i] * dv;
    if (i < KCODES) ncs[i] = cs[i] * dv;
}

// ---------------------------------------------------------------------------
// bf16 MFMA screen: scores s[n][k] = ee[k] - 2*dot(x_n, e_k).
// PACKED-SCORE top-k: the 12-bit code index is OR'd into the low mantissa
// bits of the fp32 score (score quantized to 20 bits). Float compares then
// order by score with the index riding along (quantization noise 2^-12
// relative, far below the bf16 screen noise already tolerated; rescore
// recomputes exact distances for the final pick). This removes the index
// half of the top-k state: 64 -> 32 regs/lane. Live set ~160 <= 170, so
// __launch_bounds__(256, 3) now fits WITHOUT spills (round 9: 84+64 regs
// kept, rest spilled -> WRITE_SIZE 160MB; rounds 4/7: no bound -> 2 blk/CU,
// MfmaUtil 20%).
// Grid (NPTS/128, 8): block = 128 pts x 512 codes (one code-eighth), 4
// chunks of 128 codes (64 K-steps); emits approx-top-4 (exact top-2) packed
// per (point, eighth) into 32-slot scrO.
// K-loop: TRIPLE-buffered LDS, 2-steps-ahead staging, counted s_waitcnt
// vmcnt(4) per step. ee[] staged to an LDS table (off the vmcnt FIFO).
// LDS chunk-XOR-swizzle p = kc ^ ((row>>2)&3) keeps frag ds_read_b128
// 2-way-per-bank (free, m136). Buffer index rotated incrementally (no %3).
#define INS4P(p_)  do {                                                     \
    bool l0 = (p_) < m0, l1 = (p_) < m1, l2 = (p_) < m2, l3 = (p_) < m3;    \
    m3 = l2 ? m2 : (l3 ? (p_) : m3);                                        \
    m2 = l1 ? m1 : (l2 ? (p_) : m2);                                        \
    m1 = l0 ? m0 : (l1 ? (p_) : m1);                                        \
    m0 = l0 ? (p_) : m0;                                                    \
} while (0)

__global__ __launch_bounds__(256, 3)
void screen_kernel(const u16* __restrict__ xb, const u16* __restrict__ eb,
                   const float* __restrict__ ee,
                   float* __restrict__ scrO) {
    // [buf 0..2][A/B][128 rows * 32 k] bf16 = 48 KiB; reduction array aliases
    // buffer 0 after the K loop (dead by then). eeS: 2 KiB ee table.
    __shared__ __align__(16) u16 S[3][2][128 * 32];
    __shared__ float eeS[512];

    const int tid = threadIdx.x;
    const int w = tid >> 6, lane = tid & 63;
    const int wy = w >> 1, wx = w & 1;
    const int tx = lane & 15, g = lane >> 4;
    const int n0 = blockIdx.x * 128;
    const int hf = blockIdx.y;                 // code eighth 0..7
    const int hbase = hf * 512;

    // per-lane running top-2 per row-slot (fi*4+r), packed score|idx
    float v1[16], v2[16];
#pragma unroll
    for (int s = 0; s < 16; ++s) { v1[s] = FLT_MAX; v2[s] = FLT_MAX; }

    // hoisted per-lane ds_read element offsets (within one buffer's A/B region)
    int aoff[4], boff[4];
#pragma unroll
    for (int fi = 0; fi < 4; ++fi) {
        int row = wy * 64 + 16 * fi + tx;
        int ph = g ^ ((row >> 2) & 3);
        aoff[fi] = row * 32 + ph * 8;
    }
#pragma unroll
    for (int fj = 0; fj < 4; ++fj) {
        int row = wx * 64 + 16 * fj + tx;
        int ph = g ^ ((row >> 2) & 3);
        boff[fj] = 4096 + row * 32 + ph * 8;   // B region is +4096 elems
    }
    const int eoff = wx * 64 + tx;             // per-lane ee table offset

    // staging lane constants: instr t covers rows [16t,16t+16); lane l ->
    // row 16t+(l>>2), physical 16B-chunk l&3 holds logical chunk (l&3)^(l>>4)
    const int kc = (lane & 3) ^ (lane >> 4);
    const int srow = lane >> 2;
    const int ta = 2 * w, tb = 2 * w + 1;
    const size_t aoa = (size_t)(n0 + 16 * ta + srow) * D + kc * 8;
    const size_t aob = (size_t)(n0 + 16 * tb + srow) * D + kc * 8;
    const size_t boa = (size_t)(hbase + 16 * ta + srow) * D + kc * 8;
    const size_t bob = (size_t)(hbase + 16 * tb + srow) * D + kc * 8;

    auto stage = [&](int s, int p) {
        const int ch = s >> 4;
        const size_t ko = (size_t)((s & 15) * 32);
        const size_t co = (size_t)ch * (128 * D);
        async16(&S[p][0][ta * 512], xb + aoa + ko);
        async16(&S[p][0][tb * 512], xb + aob + ko);
        async16(&S[p][1][ta * 512], eb + boa + co + ko);
        async16(&S[p][1][tb * 512], eb + bob + co + ko);
    };

    // ee -> LDS table (512 entries for this eighth); compiler drains these
    // global loads before the ds_writes, so they stay off the staging FIFO.
#pragma unroll
    for (int q = 0; q < 2; ++q) eeS[tid + 256 * q] = ee[hbase + tid + 256 * q];

    // prologue: fill buffers 0 and 1; drain buffer 0 only (counted wait).
    stage(0, 0);
    stage(1, 1);
    asm volatile("s_waitcnt vmcnt(4)" ::: "memory");
    __builtin_amdgcn_s_barrier();

    const u16* Sbase = &S[0][0][0];
    int cur = 0;   // buffer of step s; stage target = cur+2 mod 3 = cur-1 mod 3

    for (int c = 0; c < 4; ++c) {
        f32x4 acc[4][4];
#pragma unroll
        for (int fi = 0; fi < 4; ++fi)
#pragma unroll
            for (int fj = 0; fj < 4; ++fj) acc[fi][fj] = (f32x4){0.f, 0.f, 0.f, 0.f};

        for (int kk = 0; kk < 16; ++kk) {
            const int s = c * 16 + kk;
            const u16* bp = Sbase + cur * 8192;       // uniform base, SALU

            // ds_read current buffer (stage(s) drained at end of step s-1)
            short8 af[4], bf[4];
#pragma unroll
            for (int fi = 0; fi < 4; ++fi) af[fi] = *(const short8*)(bp + aoff[fi]);
#pragma unroll
            for (int fj = 0; fj < 4; ++fj) bf[fj] = *(const short8*)(bp + boff[fj]);

            // issue stage(s+2) into buffer (cur+2)%3 == (cur-1+3)%3
            if (s < 62) stage(s + 2, cur == 0 ? 2 : cur - 1);

#pragma unroll
            for (int fi = 0; fi < 4; ++fi)
#pragma unroll
                for (int fj = 0; fj < 4; ++fj)
                    acc[fi][fj] = __builtin_amdgcn_mfma_f32_16x16x32_bf16(
                        af[fi], bf[fj], acc[fi][fj], 0, 0, 0);

            if (kk == 15) {
                // chunk epilogue: fold packed scores into per-lane top-2
#pragma unroll
                for (int fj = 0; fj < 4; ++fj) {
                    int col = hbase + c * 128 + wx * 64 + 16 * fj + tx;
                    float ev = eeS[c * 128 + eoff + 16 * fj];
#pragma unroll
                    for (int fi = 0; fi < 4; ++fi)
#pragma unroll
                        for (int r = 0; r < 4; ++r) {
                            float sc = fmaf(-2.0f, acc[fi][fj][r], ev);
                            unsigned int pu = (__float_as_uint(sc) & 0xFFFFF000u)
                                              | (unsigned int)col;
                            float pv = __uint_as_float(pu);
                            const int slot = fi * 4 + r;
                            bool b1 = pv < v1[slot];
                            bool b2 = pv < v2[slot];
                            float ov = v1[slot];
                            v1[slot] = b1 ? pv : ov;
                            v2[slot] = b1 ? ov : (b2 ? pv : v2[slot]);
                        }
                }
            }

            // counted wait: drain stage(s+1) only, keep stage(s+2) in flight.
            // Tail (s>=62): no deeper stages outstanding -> full drain.
            if (s < 62) { asm volatile("s_waitcnt vmcnt(4)" ::: "memory"); }
            else        { asm volatile("s_waitcnt vmcnt(0)" ::: "memory"); }
            __builtin_amdgcn_s_barrier();
            cur = cur == 2 ? 0 : cur + 1;
        }
    }

    // cross-lane: per row, approx-top-4 (exact top-2) over the wave's 64 cols,
    // on packed values. Reduction array aliases dead tile LDS.
    float (*s_scr)[2][4] = reinterpret_cast<float (*)[2][4]>(&S[0][0][0]);

#pragma unroll
    for (int fi = 0; fi < 4; ++fi) {
#pragma unroll
        for (int r = 0; r < 4; ++r) {
            const int slot = fi * 4 + r;
            float m0 = v1[slot], m1 = v2[slot], m2 = FLT_MAX, m3 = FLT_MAX;
#pragma unroll
            for (int off = 1; off <= 8; off <<= 1) {
                float o0 = __shfl_xor(m0, off), o1 = __shfl_xor(m1, off);
                float o2 = __shfl_xor(m2, off), o3 = __shfl_xor(m3, off);
                INS4P(o0); INS4P(o1); INS4P(o2); INS4P(o3);
            }
            if (tx == 0) {
                int row = wy * 64 + 16 * fi + 4 * g + r;
                s_scr[row][wx][0] = m0; s_scr[row][wx][1] = m1;
                s_scr[row][wx][2] = m2; s_scr[row][wx][3] = m3;
            }
        }
    }
    __syncthreads();
    if (tid < 128) {
        float m0 = s_scr[tid][0][0], m1 = s_scr[tid][0][1],
              m2 = s_scr[tid][0][2], m3 = s_scr[tid][0][3];
#pragma unroll
        for (int q = 0; q < 4; ++q) INS4P(s_scr[tid][1][q]);
        int pt = n0 + tid;
        scrO[(hf * 4 + 0) * NPTS + pt] = m0;
        scrO[(hf * 4 + 1) * NPTS + pt] = m1;
        scrO[(hf * 4 + 2) * NPTS + pt] = m2;
        scrO[(hf * 4 + 3) * NPTS + pt] = m3;
    }
}

// ---------------------------------------------------------------------------
// merge the eight eighths' packed top-4 into global top-4 candidate indices
__global__ void merge32_kernel(const float* __restrict__ scrO, int* __restrict__ cand) {
    int n = blockIdx.x * 256 + threadIdx.x;
    float m0 = FLT_MAX, m1 = FLT_MAX, m2 = FLT_MAX, m3 = FLT_MAX;
#pragma unroll
    for (int c = 0; c < 32; ++c) {
        float p = scrO[c * NPTS + n];
        INS4P(p);
    }
    cand[0 * NPTS + n] = (int)(__float_as_uint(m0) & 0xFFFu);
    cand[1 * NPTS + n] = (int)(__float_as_uint(m1) & 0xFFFu);
    cand[2 * NPTS + n] = (int)(__float_as_uint(m2) & 0xFFFu);
    cand[3 * NPTS + n] = (int)(__float_as_uint(m3) & 0xFFFu);
}

// ---------------------------------------------------------------------------
// Final selection emulating numpy fp32 (verified passing - unchanged)
__global__ void rescore_kernel(const float* __restrict__ x, const float* __restrict__ emb,
                               const int* __restrict__ cand,
                               const float* __restrict__ xx_np,
                               const float* __restrict__ ee_np,
                               float* __restrict__ ind_f,
                               float* __restrict__ ncs, const float* __restrict__ decay_p) {
    int w = threadIdx.x >> 6, lane = threadIdx.x & 63;
    int n = blockIdx.x * 4 + w;
    float xxv = xx_np[n];
    float bestd = FLT_MAX; int bidx = 0x7fffffff;
#pragma unroll
    for (int c = 0; c < 4; ++c) {
        int k = cand[c * NPTS + n];
        double acc = 0.0;
#pragma unroll
        for (int i = 0; i < 8; ++i) {
            int d = lane + i * 64;
            acc += (double)emb[(size_t)k * D + d] * (double)x[(size_t)n * D + d];
        }
#pragma unroll
        for (int off = 32; off >= 1; off >>= 1) acc += __shfl_xor(acc, off);
        float mf = (float)acc;
        float t  = __fmul_rn(2.0f, mf);
        float u  = __fsub_rn(xxv, t);
        float dd = __fadd_rn(u, ee_np[k]);
        if (dd < bestd || (dd == bestd && k < bidx)) { bestd = dd; bidx = k; }
    }
    if (lane == 0) {
        ind_f[n] = (float)bidx;
        atomicAdd(&ncs[bidx], 1.0f - decay_p[0]);
    }
}

// ---------------------------------------------------------------------------
__global__ void gather_scatter_kernel(const float* __restrict__ x,
                                      const float* __restrict__ emb,
                                      const float* __restrict__ ind_f,
                                      float* __restrict__ quant, float* __restrict__ nea,
                                      const float* __restrict__ decay_p) {
    int gid = blockIdx.x * 256 + threadIdx.x;   // NPTS * (D/4)
    int n = gid >> 7, dq = gid & 127;
    int k = (int)ind_f[n];
    float4 e4 = *(const float4*)(emb + (size_t)k * D + dq * 4);
    *(float4*)(quant + (size_t)n * D + dq * 4) = e4;
    float4 x4 = *(const float4*)(x + (size_t)n * D + dq * 4);
    float wgt = 1.0f - decay_p[0];
    float* base = nea + (size_t)k * D + dq * 4;
    atomicAdd(base + 0, x4.x * wgt);
    atomicAdd(base + 1, x4.y * wgt);
    atomicAdd(base + 2, x4.z * wgt);
    atomicAdd(base + 3, x4.w * wgt);
}

// ---------------------------------------------------------------------------
__global__ void total_kernel(const float* __restrict__ ncs, float* __restrict__ total) {
    __shared__ float sd[1024];
    int t = threadIdx.x;
    sd[t] = ncs[t] + ncs[t + 1024] + ncs[t + 2048] + ncs[t + 3072];
    __syncthreads();
    for (int st = 512; st > 0; st >>= 1) {
        if (t < st) sd[t] += sd[t + st];
        __syncthreads();
    }
    if (t == 0) total[0] = sd[0];
}

__global__ void new_embed_kernel(const float* __restrict__ nea, const float* __restrict__ ncs,
                                 const float* __restrict__ total, float* __restrict__ ne) {
    int i = blockIdx.x * 256 + threadIdx.x;   // K*D
    int k = i >> 9;
    float t = total[0];
    float sm = (ncs[k] + EPSV) / (t + EPSV * (float)KCODES) * t;
    ne[i] = nea[i] / sm;
}

// ---------------------------------------------------------------------------
extern "C" void kernel_launch(void* const* d_in, const int* in_sizes, int n_in,
                              void* d_out, int out_size, void* d_ws, size_t ws_size,
                              hipStream_t stream) {
    const float* x     = (const float*)d_in[0];
    const float* emb   = (const float*)d_in[1];
    const float* cs    = (const float*)d_in[2];
    const float* ea    = (const float*)d_in[3];
    const float* decay = (const float*)d_in[4];

    float* out   = (float*)d_out;
    float* quant = out;                               // NPTS*D
    float* ind_f = out + (size_t)NPTS * D;            // NPTS
    float* ncs   = ind_f + NPTS;                      // KCODES
    float* nea   = ncs + KCODES;                      // KCODES*D
    float* ne    = nea + (size_t)KCODES * D;          // KCODES*D

    float* ws    = (float*)d_ws;
    float* ee_np = ws;                                // KCODES
    float* xx_np = ws + KCODES;                       // NPTS
    float* hold0 = xx_np + NPTS;                      // (layout hold, unused)
    int*   hold1 = (int*)(hold0 + 16 * (size_t)NPTS); // (layout hold, unused)
    int*   cand  = hold1 + 16 * (size_t)NPTS;         // 4*NPTS
    u16*   eb    = (u16*)(cand + 4 * (size_t)NPTS);   // KCODES*D bf16 (16B-aligned)
    float* total = (float*)(eb + (size_t)KCODES * D); // 1

    // bf16 x staged in the LOWER half of the quant output region; scrO lives
    // in the UPPER half (both dead before gather_scatter writes quant).
    u16*   xb    = (u16*)quant;                       // NPTS*D bf16 = 32MB
    float* scrO  = quant + (size_t)NPTS * D / 2;      // 32*NPTS packed floats

    hipLaunchKernelGGL(cvt_bf16_kernel, dim3(NPTS * D / 2048),   dim3(256), 0, stream, x, xb);
    hipLaunchKernelGGL(cvt_bf16_kernel, dim3(KCODES * D / 2048), dim3(256), 0, stream, emb, eb);
    hipLaunchKernelGGL(ee_np_kernel,    dim3(KCODES / 8),        dim3(256), 0, stream, emb, ee_np);
    hipLaunchKernelGGL(xx_np_kernel,    dim3(NPTS / 8),          dim3(256), 0, stream, x, xx_np);
    hipLaunchKernelGGL(init_kernel,     dim3(KCODES * (D / 256)), dim3(256), 0, stream, cs, ea, decay, ncs, nea);
    hipLaunchKernelGGL(screen_kernel,   dim3(NPTS / 128, 8),     dim3(256), 0, stream,
                       xb, eb, ee_np, scrO);
    hipLaunchKernelGGL(merge32_kernel,  dim3(NPTS / 256),        dim3(256), 0, stream, scrO, cand);
    hipLaunchKernelGGL(rescore_kernel,  dim3(NPTS / 4),          dim3(256), 0, stream,
                       x, emb, cand, xx_np, ee_np, ind_f, ncs, decay);
    hipLaunchKernelGGL(gather_scatter_kernel, dim3(NPTS * (D / 4) / 256), dim3(256), 0, stream,
                       x, emb, ind_f, quant, nea, decay);
    hipLaunchKernelGGL(total_kernel,    dim3(1),                 dim3(1024), 0, stream, ncs, total);
    hipLaunchKernelGGL(new_embed_kernel, dim3(KCODES * (D / 256)), dim3(256), 0, stream, nea, ncs, total, ne);
}

// Round 11
// 467.930 us; speedup vs baseline: 1.6419x; 1.3612x over previous
//
#include <hip/hip_runtime.h>
#include <float.h>

// Problem shape (fixed by setup_inputs): x[32768,512], embed[4096,512]
#define D 512
#define NPTS 32768
#define KCODES 4096
#define EPSV 1e-6f

typedef __attribute__((ext_vector_type(8))) short short8;
typedef __attribute__((ext_vector_type(4))) float f32x4;
typedef unsigned short u16;
typedef __attribute__((ext_vector_type(8))) unsigned short u16x8;

// ---------------------------------------------------------------------------
// async global->LDS, 16B per lane (dest = wave-uniform base + lane*16)
__device__ __forceinline__ void async16(void* lds, const void* gl) {
    __builtin_amdgcn_global_load_lds(
        (const __attribute__((address_space(1))) unsigned int*)gl,
        (__attribute__((address_space(3))) unsigned int*)lds,
        16, 0, 0);
}

// fp32 -> bf16 round-to-nearest-even
__device__ __forceinline__ unsigned short f2bf(float f) {
    unsigned int u = __float_as_uint(f);
    u += 0x7fffu + ((u >> 16) & 1u);
    return (unsigned short)(u >> 16);
}

__global__ void cvt_bf16_kernel(const float* __restrict__ in, u16* __restrict__ out) {
    size_t i = (size_t)(blockIdx.x * 256 + threadIdx.x) * 8;
    float4 a = *(const float4*)(in + i);
    float4 b = *(const float4*)(in + i + 4);
    u16x8 r = { f2bf(a.x), f2bf(a.y), f2bf(a.z), f2bf(a.w),
                f2bf(b.x), f2bf(b.y), f2bf(b.z), f2bf(b.w) };
    *(u16x8*)(out + i) = r;
}

// ---------------------------------------------------------------------------
// Bit-exact emulation of numpy fp32 pairwise sum of squares over a 512-row.
// (verified passing - do not change)
__device__ __forceinline__ float np_sumsq_512(const float* __restrict__ row, int l) {
    int b = l >> 3, j = l & 7;
    int base = b * 128 + j;
    float a = row[base];
    float r = __fmul_rn(a, a);
#pragma unroll
    for (int t = 1; t < 16; ++t) {
        float v = row[base + 8 * t];
        r = __fadd_rn(r, __fmul_rn(v, v));
    }
#pragma unroll
    for (int off = 1; off <= 16; off <<= 1)
        r = __fadd_rn(r, __shfl_xor(r, off));
    return r;
}

__global__ void xx_np_kernel(const float* __restrict__ x, float* __restrict__ xx_np) {
    int w = threadIdx.x >> 6, lane = threadIdx.x & 63;
    int hf = lane >> 5, l = lane & 31;
    int p = blockIdx.x * 8 + w * 2 + hf;
    float r = np_sumsq_512(x + (size_t)p * D, l);
    if (l == 0) xx_np[p] = r;
}

__global__ void ee_np_kernel(const float* __restrict__ emb, float* __restrict__ ee_np) {
    int w = threadIdx.x >> 6, lane = threadIdx.x & 63;
    int hf = lane >> 5, l = lane & 31;
    int k = blockIdx.x * 8 + w * 2 + hf;
    float r = np_sumsq_512(emb + (size_t)k * D, l);
    if (l == 0) ee_np[k] = r;
}

// ---------------------------------------------------------------------------
// init: ncs = cs*decay; zero the code histogram (nea init now lives in segsum)
__global__ void init_kernel(const float* __restrict__ cs,
                            const float* __restrict__ decay_p,
                            float* __restrict__ ncs, int* __restrict__ cnt) {
    int i = blockIdx.x * 256 + threadIdx.x;   // KCODES
    ncs[i] = cs[i] * decay_p[0];
    cnt[i] = 0;
}

// ---------------------------------------------------------------------------
// bf16 MFMA screen (verified passing round 10 - unchanged).
// PACKED-SCORE top-k: 12-bit code index in the low mantissa of the fp32
// score (quantized to 20 bits); float compares order by score with the index
// riding along. Grid (NPTS/128, 8); triple-buffered LDS, 2-ahead staging,
// counted vmcnt(4); __launch_bounds__(256,3) fits spill-free at ~160 regs.
#define INS4P(p_)  do {                                                     \
    bool l0 = (p_) < m0, l1 = (p_) < m1, l2 = (p_) < m2, l3 = (p_) < m3;    \
    m3 = l2 ? m2 : (l3 ? (p_) : m3);                                        \
    m2 = l1 ? m1 : (l2 ? (p_) : m2);                                        \
    m1 = l0 ? m0 : (l1 ? (p_) : m1);                                        \
    m0 = l0 ? (p_) : m0;                                                    \
} while (0)

__global__ __launch_bounds__(256, 3)
void screen_kernel(const u16* __restrict__ xb, const u16* __restrict__ eb,
                   const float* __restrict__ ee,
                   float* __restrict__ scrO) {
    __shared__ __align__(16) u16 S[3][2][128 * 32];
    __shared__ float eeS[512];

    const int tid = threadIdx.x;
    const int w = tid >> 6, lane = tid & 63;
    const int wy = w >> 1, wx = w & 1;
    const int tx = lane & 15, g = lane >> 4;
    const int n0 = blockIdx.x * 128;
    const int hf = blockIdx.y;                 // code eighth 0..7
    const int hbase = hf * 512;

    float v1[16], v2[16];
#pragma unroll
    for (int s = 0; s < 16; ++s) { v1[s] = FLT_MAX; v2[s] = FLT_MAX; }

    int aoff[4], boff[4];
#pragma unroll
    for (int fi = 0; fi < 4; ++fi) {
        int row = wy * 64 + 16 * fi + tx;
        int ph = g ^ ((row >> 2) & 3);
        aoff[fi] = row * 32 + ph * 8;
    }
#pragma unroll
    for (int fj = 0; fj < 4; ++fj) {
        int row = wx * 64 + 16 * fj + tx;
        int ph = g ^ ((row >> 2) & 3);
        boff[fj] = 4096 + row * 32 + ph * 8;
    }
    const int eoff = wx * 64 + tx;

    const int kc = (lane & 3) ^ (lane >> 4);
    const int srow = lane >> 2;
    const int ta = 2 * w, tb = 2 * w + 1;
    const size_t aoa = (size_t)(n0 + 16 * ta + srow) * D + kc * 8;
    const size_t aob = (size_t)(n0 + 16 * tb + srow) * D + kc * 8;
    const size_t boa = (size_t)(hbase + 16 * ta + srow) * D + kc * 8;
    const size_t bob = (size_t)(hbase + 16 * tb + srow) * D + kc * 8;

    auto stage = [&](int s, int p) {
        const int ch = s >> 4;
        const size_t ko = (size_t)((s & 15) * 32);
        const size_t co = (size_t)ch * (128 * D);
        async16(&S[p][0][ta * 512], xb + aoa + ko);
        async16(&S[p][0][tb * 512], xb + aob + ko);
        async16(&S[p][1][ta * 512], eb + boa + co + ko);
        async16(&S[p][1][tb * 512], eb + bob + co + ko);
    };

#pragma unroll
    for (int q = 0; q < 2; ++q) eeS[tid + 256 * q] = ee[hbase + tid + 256 * q];

    stage(0, 0);
    stage(1, 1);
    asm volatile("s_waitcnt vmcnt(4)" ::: "memory");
    __builtin_amdgcn_s_barrier();

    const u16* Sbase = &S[0][0][0];
    int cur = 0;

    for (int c = 0; c < 4; ++c) {
        f32x4 acc[4][4];
#pragma unroll
        for (int fi = 0; fi < 4; ++fi)
#pragma unroll
            for (int fj = 0; fj < 4; ++fj) acc[fi][fj] = (f32x4){0.f, 0.f, 0.f, 0.f};

        for (int kk = 0; kk < 16; ++kk) {
            const int s = c * 16 + kk;
            const u16* bp = Sbase + cur * 8192;

            short8 af[4], bf[4];
#pragma unroll
            for (int fi = 0; fi < 4; ++fi) af[fi] = *(const short8*)(bp + aoff[fi]);
#pragma unroll
            for (int fj = 0; fj < 4; ++fj) bf[fj] = *(const short8*)(bp + boff[fj]);

            if (s < 62) stage(s + 2, cur == 0 ? 2 : cur - 1);

#pragma unroll
            for (int fi = 0; fi < 4; ++fi)
#pragma unroll
                for (int fj = 0; fj < 4; ++fj)
                    acc[fi][fj] = __builtin_amdgcn_mfma_f32_16x16x32_bf16(
                        af[fi], bf[fj], acc[fi][fj], 0, 0, 0);

            if (kk == 15) {
#pragma unroll
                for (int fj = 0; fj < 4; ++fj) {
                    int col = hbase + c * 128 + wx * 64 + 16 * fj + tx;
                    float ev = eeS[c * 128 + eoff + 16 * fj];
#pragma unroll
                    for (int fi = 0; fi < 4; ++fi)
#pragma unroll
                        for (int r = 0; r < 4; ++r) {
                            float sc = fmaf(-2.0f, acc[fi][fj][r], ev);
                            unsigned int pu = (__float_as_uint(sc) & 0xFFFFF000u)
                                              | (unsigned int)col;
                            float pv = __uint_as_float(pu);
                            const int slot = fi * 4 + r;
                            bool b1 = pv < v1[slot];
                            bool b2 = pv < v2[slot];
                            float ov = v1[slot];
                            v1[slot] = b1 ? pv : ov;
                            v2[slot] = b1 ? ov : (b2 ? pv : v2[slot]);
                        }
                }
            }

            if (s < 62) { asm volatile("s_waitcnt vmcnt(4)" ::: "memory"); }
            else        { asm volatile("s_waitcnt vmcnt(0)" ::: "memory"); }
            __builtin_amdgcn_s_barrier();
            cur = cur == 2 ? 0 : cur + 1;
        }
    }

    float (*s_scr)[2][4] = reinterpret_cast<float (*)[2][4]>(&S[0][0][0]);

#pragma unroll
    for (int fi = 0; fi < 4; ++fi) {
#pragma unroll
        for (int r = 0; r < 4; ++r) {
            const int slot = fi * 4 + r;
            float m0 = v1[slot], m1 = v2[slot], m2 = FLT_MAX, m3 = FLT_MAX;
#pragma unroll
            for (int off = 1; off <= 8; off <<= 1) {
                float o0 = __shfl_xor(m0, off), o1 = __shfl_xor(m1, off);
                float o2 = __shfl_xor(m2, off), o3 = __shfl_xor(m3, off);
                INS4P(o0); INS4P(o1); INS4P(o2); INS4P(o3);
            }
            if (tx == 0) {
                int row = wy * 64 + 16 * fi + 4 * g + r;
                s_scr[row][wx][0] = m0; s_scr[row][wx][1] = m1;
                s_scr[row][wx][2] = m2; s_scr[row][wx][3] = m3;
            }
        }
    }
    __syncthreads();
    if (tid < 128) {
        float m0 = s_scr[tid][0][0], m1 = s_scr[tid][0][1],
              m2 = s_scr[tid][0][2], m3 = s_scr[tid][0][3];
#pragma unroll
        for (int q = 0; q < 4; ++q) INS4P(s_scr[tid][1][q]);
        int pt = n0 + tid;
        scrO[(hf * 4 + 0) * NPTS + pt] = m0;
        scrO[(hf * 4 + 1) * NPTS + pt] = m1;
        scrO[(hf * 4 + 2) * NPTS + pt] = m2;
        scrO[(hf * 4 + 3) * NPTS + pt] = m3;
    }
}

// ---------------------------------------------------------------------------
// merge the eight eighths' packed top-4 into global top-4 candidate indices
__global__ void merge32_kernel(const float* __restrict__ scrO, int* __restrict__ cand) {
    int n = blockIdx.x * 256 + threadIdx.x;
    float m0 = FLT_MAX, m1 = FLT_MAX, m2 = FLT_MAX, m3 = FLT_MAX;
#pragma unroll
    for (int c = 0; c < 32; ++c) {
        float p = scrO[c * NPTS + n];
        INS4P(p);
    }
    cand[0 * NPTS + n] = (int)(__float_as_uint(m0) & 0xFFFu);
    cand[1 * NPTS + n] = (int)(__float_as_uint(m1) & 0xFFFu);
    cand[2 * NPTS + n] = (int)(__float_as_uint(m2) & 0xFFFu);
    cand[3 * NPTS + n] = (int)(__float_as_uint(m3) & 0xFFFu);
}

// ---------------------------------------------------------------------------
// Final selection emulating numpy fp32 (verified passing - unchanged)
__global__ void rescore_kernel(const float* __restrict__ x, const float* __restrict__ emb,
                               const int* __restrict__ cand,
                               const float* __restrict__ xx_np,
                               const float* __restrict__ ee_np,
                               float* __restrict__ ind_f,
                               float* __restrict__ ncs, const float* __restrict__ decay_p) {
    int w = threadIdx.x >> 6, lane = threadIdx.x & 63;
    int n = blockIdx.x * 4 + w;
    float xxv = xx_np[n];
    float bestd = FLT_MAX; int bidx = 0x7fffffff;
#pragma unroll
    for (int c = 0; c < 4; ++c) {
        int k = cand[c * NPTS + n];
        double acc = 0.0;
#pragma unroll
        for (int i = 0; i < 8; ++i) {
            int d = lane + i * 64;
            acc += (double)emb[(size_t)k * D + d] * (double)x[(size_t)n * D + d];
        }
#pragma unroll
        for (int off = 32; off >= 1; off >>= 1) acc += __shfl_xor(acc, off);
        float mf = (float)acc;
        float t  = __fmul_rn(2.0f, mf);
        float u  = __fsub_rn(xxv, t);
        float dd = __fadd_rn(u, ee_np[k]);
        if (dd < bestd || (dd == bestd && k < bidx)) { bestd = dd; bidx = k; }
    }
    if (lane == 0) {
        ind_f[n] = (float)bidx;
        atomicAdd(&ncs[bidx], 1.0f - decay_p[0]);
    }
}

// ---------------------------------------------------------------------------
// counting-sort pipeline replacing the atomic scatter (round-10 hotspot:
// gather_scatter 227us, WRITE_SIZE 320MB from 16.7M fp32 atomics into nea).
__global__ void hist_kernel(const float* __restrict__ ind_f, int* __restrict__ cnt) {
    int n = blockIdx.x * 256 + threadIdx.x;
    atomicAdd(&cnt[(int)ind_f[n]], 1);
}

// single-block exclusive prefix sum over KCODES=4096 (1024 thr x 4 elems)
__global__ void scan_kernel(const int* __restrict__ cnt,
                            int* __restrict__ off, int* __restrict__ cur) {
    __shared__ int sd[1024];
    int t = threadIdx.x;
    int b = t * 4;
    int c0 = cnt[b], c1 = cnt[b + 1], c2 = cnt[b + 2], c3 = cnt[b + 3];
    int s = c0 + c1 + c2 + c3;
    sd[t] = s;
    __syncthreads();
    for (int st = 1; st < 1024; st <<= 1) {
        int v = (t >= st) ? sd[t - st] : 0;
        __syncthreads();
        sd[t] += v;
        __syncthreads();
    }
    int ex = sd[t] - s;   // exclusive prefix of this thread's 4-group
    off[b] = ex;           cur[b] = ex;
    off[b + 1] = ex + c0;  cur[b + 1] = ex + c0;
    off[b + 2] = ex + c0 + c1;  cur[b + 2] = ex + c0 + c1;
    off[b + 3] = ex + c0 + c1 + c2;  cur[b + 3] = ex + c0 + c1 + c2;
}

__global__ void scatter_kernel(const float* __restrict__ ind_f,
                               int* __restrict__ cur, int* __restrict__ list) {
    int n = blockIdx.x * 256 + threadIdx.x;
    int k = (int)ind_f[n];
    int pos = atomicAdd(&cur[k], 1);
    list[pos] = n;
}

// quant gather only (no atomics): quant[n] = embed[ind[n]]
__global__ void quant_gather_kernel(const float* __restrict__ emb,
                                    const float* __restrict__ ind_f,
                                    float* __restrict__ quant) {
    int gid = blockIdx.x * 256 + threadIdx.x;   // NPTS * (D/4)
    int n = gid >> 7, dq = gid & 127;
    int k = (int)ind_f[n];
    float4 e4 = *(const float4*)(emb + (size_t)k * D + dq * 4);
    *(float4*)(quant + (size_t)n * D + dq * 4) = e4;
}

// one wave per code: nea[k] = ea[k]*decay + (sum of its x rows)*(1-decay)
__global__ void segsum_kernel(const float* __restrict__ x, const float* __restrict__ ea,
                              const int* __restrict__ off, const int* __restrict__ cnt,
                              const int* __restrict__ list,
                              const float* __restrict__ decay_p,
                              float* __restrict__ nea) {
    int w = threadIdx.x >> 6, lane = threadIdx.x & 63;
    int k = blockIdx.x * 4 + w;
    int start = off[k], n = cnt[k];
    float a0 = 0.f, a1 = 0.f, a2 = 0.f, a3 = 0.f;
    float b0 = 0.f, b1 = 0.f, b2 = 0.f, b3 = 0.f;
    for (int i = 0; i < n; ++i) {
        int p = list[start + i];
        const float4* xp = (const float4*)(x + (size_t)p * D);
        float4 u = xp[lane];        // elems [4*lane, 4*lane+3]
        float4 v = xp[lane + 64];   // elems [256+4*lane, ...]
        a0 += u.x; a1 += u.y; a2 += u.z; a3 += u.w;
        b0 += v.x; b1 += v.y; b2 += v.z; b3 += v.w;
    }
    float dv = decay_p[0], wg = 1.0f - dv;
    const float4* ep = (const float4*)(ea + (size_t)k * D);
    float4 e0 = ep[lane], e1 = ep[lane + 64];
    float4 r0 = { e0.x * dv + a0 * wg, e0.y * dv + a1 * wg,
                  e0.z * dv + a2 * wg, e0.w * dv + a3 * wg };
    float4 r1 = { e1.x * dv + b0 * wg, e1.y * dv + b1 * wg,
                  e1.z * dv + b2 * wg, e1.w * dv + b3 * wg };
    float4* np_ = (float4*)(nea + (size_t)k * D);
    np_[lane] = r0;
    np_[lane + 64] = r1;
}

// ---------------------------------------------------------------------------
__global__ void total_kernel(const float* __restrict__ ncs, float* __restrict__ total) {
    __shared__ float sd[1024];
    int t = threadIdx.x;
    sd[t] = ncs[t] + ncs[t + 1024] + ncs[t + 2048] + ncs[t + 3072];
    __syncthreads();
    for (int st = 512; st > 0; st >>= 1) {
        if (t < st) sd[t] += sd[t + st];
        __syncthreads();
    }
    if (t == 0) total[0] = sd[0];
}

__global__ void new_embed_kernel(const float* __restrict__ nea, const float* __restrict__ ncs,
                                 const float* __restrict__ total, float* __restrict__ ne) {
    int i = blockIdx.x * 256 + threadIdx.x;   // K*D
    int k = i >> 9;
    float t = total[0];
    float sm = (ncs[k] + EPSV) / (t + EPSV * (float)KCODES) * t;
    ne[i] = nea[i] / sm;
}

// ---------------------------------------------------------------------------
extern "C" void kernel_launch(void* const* d_in, const int* in_sizes, int n_in,
                              void* d_out, int out_size, void* d_ws, size_t ws_size,
                              hipStream_t stream) {
    const float* x     = (const float*)d_in[0];
    const float* emb   = (const float*)d_in[1];
    const float* cs    = (const float*)d_in[2];
    const float* ea    = (const float*)d_in[3];
    const float* decay = (const float*)d_in[4];

    float* out   = (float*)d_out;
    float* quant = out;                               // NPTS*D
    float* ind_f = out + (size_t)NPTS * D;            // NPTS
    float* ncs   = ind_f + NPTS;                      // KCODES
    float* nea   = ncs + KCODES;                      // KCODES*D
    float* ne    = nea + (size_t)KCODES * D;          // KCODES*D

    float* ws    = (float*)d_ws;
    float* ee_np = ws;                                // KCODES
    float* xx_np = ws + KCODES;                       // NPTS
    int*   cnt   = (int*)(xx_np + NPTS);              // KCODES
    int*   off   = cnt + KCODES;                      // KCODES
    int*   curp  = off + KCODES;                      // KCODES
    int*   list  = curp + KCODES;                     // NPTS
    float* hold0 = (float*)(list + NPTS);             // pad to keep layout roomy
    int*   cand  = (int*)(hold0 + 8 * (size_t)NPTS);  // 4*NPTS
    u16*   eb    = (u16*)(cand + 4 * (size_t)NPTS);   // KCODES*D bf16 (16B-aligned)
    float* total = (float*)(eb + (size_t)KCODES * D); // 1

    // bf16 x staged in the LOWER half of the quant output region; scrO lives
    // in the UPPER half (both dead before quant_gather writes quant).
    u16*   xb    = (u16*)quant;                       // NPTS*D bf16 = 32MB
    float* scrO  = quant + (size_t)NPTS * D / 2;      // 32*NPTS packed floats

    hipLaunchKernelGGL(cvt_bf16_kernel, dim3(NPTS * D / 2048),   dim3(256), 0, stream, x, xb);
    hipLaunchKernelGGL(cvt_bf16_kernel, dim3(KCODES * D / 2048), dim3(256), 0, stream, emb, eb);
    hipLaunchKernelGGL(ee_np_kernel,    dim3(KCODES / 8),        dim3(256), 0, stream, emb, ee_np);
    hipLaunchKernelGGL(xx_np_kernel,    dim3(NPTS / 8),          dim3(256), 0, stream, x, xx_np);
    hipLaunchKernelGGL(init_kernel,     dim3(KCODES / 256),      dim3(256), 0, stream, cs, decay, ncs, cnt);
    hipLaunchKernelGGL(screen_kernel,   dim3(NPTS / 128, 8),     dim3(256), 0, stream,
                       xb, eb, ee_np, scrO);
    hipLaunchKernelGGL(merge32_kernel,  dim3(NPTS / 256),        dim3(256), 0, stream, scrO, cand);
    hipLaunchKernelGGL(rescore_kernel,  dim3(NPTS / 4),          dim3(256), 0, stream,
                       x, emb, cand, xx_np, ee_np, ind_f, ncs, decay);
    hipLaunchKernelGGL(hist_kernel,     dim3(NPTS / 256),        dim3(256), 0, stream, ind_f, cnt);
    hipLaunchKernelGGL(scan_kernel,     dim3(1),                 dim3(1024), 0, stream, cnt, off, curp);
    hipLaunchKernelGGL(scatter_kernel,  dim3(NPTS / 256),        dim3(256), 0, stream, ind_f, curp, list);
    hipLaunchKernelGGL(quant_gather_kernel, dim3(NPTS * (D / 4) / 256), dim3(256), 0, stream,
                       emb, ind_f, quant);
    hipLaunchKernelGGL(segsum_kernel,   dim3(KCODES / 4),        dim3(256), 0, stream,
                       x, ea, off, cnt, list, decay, nea);
    hipLaunchKernelGGL(total_kernel,    dim3(1),                 dim3(1024), 0, stream, ncs, total);
    hipLaunchKernelGGL(new_embed_kernel, dim3(KCODES * (D / 256)), dim3(256), 0, stream, nea, ncs, total, ne);
}